// Round 5
// baseline (945.363 us; speedup 1.0000x reference)
//
#include <hip/hip_runtime.h>
#include <hip/hip_cooperative_groups.h>
#include <math.h>

namespace cg = cooperative_groups;

// OHNM loss: pos BCE sum + top-k(600000) negative softplus sum, mean over 800000.
//
// R5: ONE cooperative kernel (grid.sync between phases) replaces 6 dispatches.
//   P0 zero ctrl -> P1 main pass (pos_sum + wave-aggregated compact of negative
//   keys >= K0=f2key(1.0)) -> P2 hist1 (fine radix: (k-K0)>>14, 4096 bins over
//   x in [1,256)) -> P3 scan1 + "sure" softplus sum (bin>b1) + hist2(bits 13:4)
//   -> P4 scan2 + l2-sure sum + hist3/histF3(bits 3:0, counts + float sums)
//   -> P5 block0 finalizes: exact threshold H, ties via r3*softplus(H).
// R4 lesson: per-lane same-address LDS atomics serialized the main pass (60 us
// even with L3-resident inputs). Wave-ballot aggregation = 1 LDS atomic/wave.
// Fallback (cand_count < Kneg): coarse k>>20 radix + re-stream x,y in P2-P4.
// Exact for any input; never triggered for this one.

#define NB1 4096
#define NB2 1024
#define NB3 1024
#define LBUF_CAP 4096
#define K0 0xBF800000u           // f2key(1.0f)
#define CTRL_WORDS_PAD 8192      // 32 KB reserved for Ctrl

struct Ctrl {
    unsigned hist1[NB1];
    unsigned hist2[NB2];
    unsigned hist3[NB3];
    float    histF3[NB3];        // per-l3-bin softplus sums
    float    pos_sum;
    float    sum_sure;           // softplus sum, bin1 > b1
    float    sum_l2;             // softplus sum, bin1==b1 && l2 > b2
    unsigned cand_count;
};

__device__ __forceinline__ unsigned f2key(float x) {
    unsigned u = __float_as_uint(x);
    return (u & 0x80000000u) ? ~u : (u | 0x80000000u);
}
__device__ __forceinline__ float key2f(unsigned k) {
    unsigned u = (k & 0x80000000u) ? (k & 0x7FFFFFFFu) : ~k;
    return __uint_as_float(u);
}
__device__ __forceinline__ float softplusf(float x) {
    return fmaxf(x, 0.0f) + __logf(1.0f + __expf(-fabsf(x)));
}
__device__ __forceinline__ float wred(float v) {
    v += __shfl_down(v, 32); v += __shfl_down(v, 16); v += __shfl_down(v, 8);
    v += __shfl_down(v, 4);  v += __shfl_down(v, 2);  v += __shfl_down(v, 1);
    return v;
}
__device__ __forceinline__ unsigned bin1_of(unsigned k, bool fb) {
    if (fb) return k >> 20;
    unsigned kp = k - K0;            // only called with k >= K0 in normal mode
    unsigned b = kp >> 14;
    return b > 4095u ? 4095u : b;    // clamp: x >= 256 (never the boundary here)
}
__device__ __forceinline__ unsigned bin2_of(unsigned k, bool fb) {
    return fb ? ((k >> 10) & 1023u) : (((k - K0) >> 4) & 1023u);
}
__device__ __forceinline__ unsigned bin3_of(unsigned k, bool fb) {
    return fb ? (k & 1023u) : ((k - K0) & 15u);
}

// descending rank-select over a global histogram; redundant per block.
// All 256 threads must call. Returns first bin (from top) where cum >= R and
// r = R - count_strictly_above (>= 1).
__device__ void scan_desc(const unsigned* __restrict__ hist, int nbins, unsigned R,
                          unsigned* s_scan, unsigned* bin_out, unsigned* r_out) {
    const int per = nbins / 256;
    const int t = threadIdx.x;
    unsigned local[16];
    unsigned s = 0;
    for (int j = 0; j < per; ++j) {
        local[j] = hist[nbins - 1 - (t * per + j)];
        s += local[j];
    }
    if (t == 0) { s_scan[256] = 0u; s_scan[257] = 1u; }
    s_scan[t] = s;
    __syncthreads();
    for (int off = 1; off < 256; off <<= 1) {
        unsigned v = (t >= off) ? s_scan[t - off] : 0u;
        __syncthreads();
        s_scan[t] += v;
        __syncthreads();
    }
    const unsigned incl = s_scan[t];
    const unsigned excl = incl - s;
    if (excl < R && incl >= R) {
        unsigned cum = excl;
        for (int j = 0; j < per; ++j) {
            if (cum + local[j] >= R) {
                s_scan[256] = (unsigned)(nbins - 1 - (t * per + j));
                s_scan[257] = R - cum;
                break;
            }
            cum += local[j];
        }
    }
    __syncthreads();
    *bin_out = s_scan[256];
    *r_out = s_scan[257];
    __syncthreads();
}

__global__ __launch_bounds__(256)
void k_all(const float* __restrict__ x, const float* __restrict__ y,
           const int* __restrict__ pos_num, float* __restrict__ out,
           unsigned* __restrict__ ws, unsigned cap, int n) {
    cg::grid_group grid = cg::this_grid();
    Ctrl* ctrl = (Ctrl*)ws;
    unsigned* cand = ws + CTRL_WORDS_PAD;

    __shared__ unsigned s_h[NB1];      // lbuf (P1) / histograms (P2-P4)
    __shared__ float    s_f[NB3];      // histF3 (P4)
    __shared__ unsigned s_scan[258];
    __shared__ unsigned s_u[2];        // lcount, gbase
    __shared__ float    s_red;

    const int tid = threadIdx.x;
    const int lane = tid & 63;
    const unsigned gtid = blockIdx.x * blockDim.x + tid;
    const unsigned gstride = gridDim.x * blockDim.x;
    const unsigned Kneg = (unsigned)(pos_num[0] * 3);

    // ---------------- P0: zero control region ----------------
    for (unsigned i = gtid; i < CTRL_WORDS_PAD; i += gstride) ws[i] = 0u;
    grid.sync();

    // ---------------- P1: main pass ----------------
    if (tid == 0) { s_u[0] = 0u; s_red = 0.0f; }
    __syncthreads();
    {
        float ps = 0.0f;
        const int n4 = n >> 2;
        const float4* x4 = (const float4*)x;
        const float4* y4 = (const float4*)y;
        for (unsigned i = gtid; i < (unsigned)n4; i += gstride) {
            float4 xv = x4[i];
            float4 yv = y4[i];
            float xs[4] = {xv.x, xv.y, xv.z, xv.w};
            float ys[4] = {yv.x, yv.y, yv.z, yv.w};
#pragma unroll
            for (int c = 0; c < 4; ++c) {
                bool pos = ys[c] > 0.0f;
                if (pos) ps += softplusf(-xs[c]);
                unsigned k = f2key(xs[c]);
                bool cnd = (!pos) && (k >= K0);
                unsigned long long mask = __ballot(cnd);
                if (mask) {
                    unsigned pfx = __popcll(mask & ((1ull << lane) - 1ull));
                    int leader = __ffsll((unsigned long long)mask) - 1;
                    unsigned base = 0;
                    if (lane == leader)
                        base = atomicAdd(&s_u[0], (unsigned)__popcll(mask));
                    base = __shfl(base, leader);
                    if (cnd) {
                        unsigned p = base + pfx;
                        if (p < LBUF_CAP) s_h[p] = k;
                        else {  // overflow fallback (lambda~1270, cap 4096)
                            unsigned gi = atomicAdd(&ctrl->cand_count, 1u);
                            if (gi < cap) cand[gi] = k;
                        }
                    }
                }
            }
        }
        if (gtid == 0) {    // tail (n % 4)
            for (int i = (n >> 2) << 2; i < n; ++i) {
                float xs = x[i], ysv = y[i];
                if (ysv > 0.0f) ps += softplusf(-xs);
                else {
                    unsigned k = f2key(xs);
                    if (k >= K0) {
                        unsigned p = atomicAdd(&s_u[0], 1u);
                        if (p < LBUF_CAP) s_h[p] = k;
                        else {
                            unsigned gi = atomicAdd(&ctrl->cand_count, 1u);
                            if (gi < cap) cand[gi] = k;
                        }
                    }
                }
            }
        }
        __syncthreads();
        ps = wred(ps);
        if (lane == 0) atomicAdd(&s_red, ps);
        __syncthreads();
        const unsigned m = s_u[0] < LBUF_CAP ? s_u[0] : LBUF_CAP;
        if (tid == 0) {
            s_u[1] = atomicAdd(&ctrl->cand_count, m);
            atomicAdd(&ctrl->pos_sum, s_red);
        }
        __syncthreads();
        const unsigned gbase = s_u[1];
        for (unsigned i = tid; i < m; i += 256) {
            unsigned gi = gbase + i;
            if (gi < cap) cand[gi] = s_h[i];
        }
    }
    __threadfence();
    grid.sync();

    // ---------------- P2: level-1 histogram ----------------
    const unsigned mAll = ctrl->cand_count;
    const unsigned m = mAll < cap ? mAll : cap;
    const bool fb = (mAll < Kneg);     // fallback: some top-k keys below K0
    for (unsigned i = tid; i < NB1; i += 256) s_h[i] = 0u;
    __syncthreads();
    if (blockIdx.x < 256) {
        for (unsigned i = blockIdx.x * 256 + tid; i < m; i += 256 * 256)
            atomicAdd(&s_h[bin1_of(cand[i], fb)], 1u);
    }
    if (fb) {
        for (unsigned i = gtid; i < (unsigned)n; i += gstride)
            if (y[i] == 0.0f) {
                unsigned k = f2key(x[i]);
                if (k < K0) atomicAdd(&s_h[bin1_of(k, true)], 1u);
            }
    }
    __syncthreads();
    for (unsigned i = tid; i < NB1; i += 256) {
        unsigned v = s_h[i];
        if (v) atomicAdd(&ctrl->hist1[i], v);
    }
    __threadfence();
    grid.sync();

    // ------- P3: scan1 + sure-sum (bin>b1) + level-2 histogram -------
    unsigned b1, r1;
    scan_desc(ctrl->hist1, NB1, Kneg, s_scan, &b1, &r1);
    for (unsigned i = tid; i < NB2; i += 256) s_h[i] = 0u;
    if (tid == 0) s_red = 0.0f;
    __syncthreads();
    {
        float ss = 0.0f;
        for (unsigned i = gtid; i < m; i += gstride) {
            unsigned k = cand[i];
            unsigned b = bin1_of(k, fb);
            if (b > b1) ss += softplusf(key2f(k));
            else if (b == b1) atomicAdd(&s_h[bin2_of(k, fb)], 1u);
        }
        if (fb) {
            for (unsigned i = gtid; i < (unsigned)n; i += gstride)
                if (y[i] == 0.0f) {
                    unsigned k = f2key(x[i]);
                    if (k < K0) {
                        unsigned b = bin1_of(k, true);
                        if (b > b1) ss += softplusf(key2f(k));
                        else if (b == b1) atomicAdd(&s_h[bin2_of(k, true)], 1u);
                    }
                }
        }
        __syncthreads();
        ss = wred(ss);
        if (lane == 0) atomicAdd(&s_red, ss);
        __syncthreads();
        for (unsigned i = tid; i < NB2; i += 256) {
            unsigned v = s_h[i];
            if (v) atomicAdd(&ctrl->hist2[i], v);
        }
        if (tid == 0) atomicAdd(&ctrl->sum_sure, s_red);
    }
    __threadfence();
    grid.sync();

    // ------- P4: scan2 + l2-sure-sum + level-3 hist (counts + float sums) ----
    unsigned b2, r2;
    scan_desc(ctrl->hist2, NB2, r1, s_scan, &b2, &r2);
    for (unsigned i = tid; i < NB3; i += 256) { s_h[i] = 0u; s_f[i] = 0.0f; }
    if (tid == 0) s_red = 0.0f;
    __syncthreads();
    {
        float s2 = 0.0f;
        for (unsigned i = gtid; i < m; i += gstride) {
            unsigned k = cand[i];
            if (bin1_of(k, fb) == b1) {
                unsigned l2 = bin2_of(k, fb);
                if (l2 > b2) s2 += softplusf(key2f(k));
                else if (l2 == b2) {
                    unsigned l3 = bin3_of(k, fb);
                    atomicAdd(&s_h[l3], 1u);
                    atomicAdd(&s_f[l3], softplusf(key2f(k)));
                }
            }
        }
        if (fb) {
            for (unsigned i = gtid; i < (unsigned)n; i += gstride)
                if (y[i] == 0.0f) {
                    unsigned k = f2key(x[i]);
                    if (k < K0 && bin1_of(k, true) == b1) {
                        unsigned l2 = bin2_of(k, true);
                        if (l2 > b2) s2 += softplusf(key2f(k));
                        else if (l2 == b2) {
                            unsigned l3 = bin3_of(k, true);
                            atomicAdd(&s_h[l3], 1u);
                            atomicAdd(&s_f[l3], softplusf(key2f(k)));
                        }
                    }
                }
        }
        __syncthreads();
        s2 = wred(s2);
        if (lane == 0) atomicAdd(&s_red, s2);
        __syncthreads();
        for (unsigned i = tid; i < NB3; i += 256) {
            if (s_h[i]) atomicAdd(&ctrl->hist3[i], s_h[i]);
            if (s_f[i] != 0.0f) atomicAdd(&ctrl->histF3[i], s_f[i]);
        }
        if (tid == 0) atomicAdd(&ctrl->sum_l2, s_red);
    }
    __threadfence();
    grid.sync();

    // ---------------- P5: finalize (block 0) ----------------
    if (blockIdx.x == 0) {
        unsigned c3, r3;
        scan_desc(ctrl->hist3, NB3, r2, s_scan, &c3, &r3);
        if (tid == 0) {
            float contrib3 = 0.0f;
            for (unsigned j = c3 + 1; j < NB3; ++j) contrib3 += ctrl->histF3[j];
            unsigned H = fb ? ((b1 << 20) | (b2 << 10) | c3)
                            : (K0 + ((b1 << 14) | (b2 << 4) | c3));
            float total = ctrl->pos_sum + ctrl->sum_sure + ctrl->sum_l2 +
                          contrib3 + (float)r3 * softplusf(key2f(H));
            int p = pos_num[0];
            out[0] = total / (float)(4 * p);
        }
    }
}

extern "C" void kernel_launch(void* const* d_in, const int* in_sizes, int n_in,
                              void* d_out, int out_size, void* d_ws, size_t ws_size,
                              hipStream_t stream) {
    const float* x = (const float*)d_in[0];
    const float* y = (const float*)d_in[1];
    const int* pos_num = (const int*)d_in[2];
    float* out = (float*)d_out;
    int n = in_sizes[0];

    unsigned* ws = (unsigned*)d_ws;
    unsigned cap = (ws_size > (size_t)(CTRL_WORDS_PAD * 4))
                       ? (unsigned)((ws_size - CTRL_WORDS_PAD * 4) / 4)
                       : 0u;

    void* args[] = {(void*)&x, (void*)&y, (void*)&pos_num, (void*)&out,
                    (void*)&ws, (void*)&cap, (void*)&n};
    hipLaunchCooperativeKernel((const void*)k_all, dim3(1024), dim3(256),
                               args, 0, stream);
}

// Round 6
// 203.206 us; speedup vs baseline: 4.6522x; 4.6522x over previous
//
#include <hip/hip_runtime.h>
#include <math.h>

// OHNM loss: pos BCE sum + top-k(600000) negative softplus sum, mean over 800000.
//
// R6: multi-dispatch (kernel boundaries = free device-wide barriers; R5 showed
// grid.sync() costs ~170us/sync from same-line polling across 8 XCDs).
//  k_init -> k_main (67MB pass: pos_sum + WAVE-BALLOT-aggregated compact of
//  negative keys >= K0=f2key(1.0); R4's per-lane LDS atomics were 60us)
//  -> k_h1 (L1 hist of cand) -> k_h2 (scan1 + sure-sum + L2 hist)
//  -> k_h3 (scan2 + l2-sure-sum + L3 hist w/ per-bin softplus sums)
//  -> k_fin (1 block: exact threshold H, ties = r3*softplus(H)).
// Normal binning: L1=(k>>14)-(K0>>14) [4096 bins, exact for x in [1,256)],
// L2=bits13:4, L3=bits3:0 -> ties-bin keys fully determined. ~2.2K keys hit
// the boundary bin so h2/h3 use direct scattered global atomics.
// hard mode (cand shortfall or x>=256): coarse k>>20/k>>10/k&1023 + x,y
// re-stream (R4's proven path). Deterministic per input; never triggers here.

#define NB1 4096
#define NB2 1024
#define NB3 1024
#define LBUF_CAP 4096
#define K0 0xBF800000u             // f2key(1.0f)
#define C14 (K0 >> 14)
#define FINE_LIMIT 0xC3800000u     // f2key(256.0f)
#define CTRL_WORDS 8192            // 32 KB reserved for Ctrl

struct Ctrl {
    unsigned hist1[NB1];
    unsigned hist2[NB2];
    unsigned hist3[NB3];
    float    histF3[NB3];          // per-L3-bin softplus sums
    float    pos_sum;
    float    sum_sure;             // softplus sum, bin1 > b1
    float    sum_l2;               // softplus sum, bin1==b1 && l2 > b2
    unsigned cand_count;
    unsigned maxkey;
    unsigned b1, r1, b2, r2;       // stage results (cross-dispatch visible)
};

__device__ __forceinline__ unsigned f2key(float x) {
    unsigned u = __float_as_uint(x);
    return (u & 0x80000000u) ? ~u : (u | 0x80000000u);
}
__device__ __forceinline__ float key2f(unsigned k) {
    unsigned u = (k & 0x80000000u) ? (k & 0x7FFFFFFFu) : ~k;
    return __uint_as_float(u);
}
__device__ __forceinline__ float softplusf(float x) {
    return fmaxf(x, 0.0f) + __logf(1.0f + __expf(-fabsf(x)));
}
__device__ __forceinline__ float wred(float v) {
    v += __shfl_down(v, 32); v += __shfl_down(v, 16); v += __shfl_down(v, 8);
    v += __shfl_down(v, 4);  v += __shfl_down(v, 2);  v += __shfl_down(v, 1);
    return v;
}
__device__ __forceinline__ unsigned wredmax(unsigned v) {
    v = max(v, (unsigned)__shfl_down((int)v, 32));
    v = max(v, (unsigned)__shfl_down((int)v, 16));
    v = max(v, (unsigned)__shfl_down((int)v, 8));
    v = max(v, (unsigned)__shfl_down((int)v, 4));
    v = max(v, (unsigned)__shfl_down((int)v, 2));
    v = max(v, (unsigned)__shfl_down((int)v, 1));
    return v;
}
__device__ __forceinline__ unsigned bin1_of(unsigned k, bool hard) {
    return hard ? (k >> 20) : ((k >> 14) - C14);
}
__device__ __forceinline__ unsigned bin2_of(unsigned k, bool hard) {
    return hard ? ((k >> 10) & 1023u) : ((k >> 4) & 1023u);
}
__device__ __forceinline__ unsigned bin3_of(unsigned k, bool hard) {
    return hard ? (k & 1023u) : (k & 15u);
}

// descending rank-select over a global histogram; all 256 threads call.
// first bin (from top) with cum >= R; r = R - count_strictly_above (>= 1).
__device__ void scan_desc(const unsigned* __restrict__ hist, int nbins, unsigned R,
                          unsigned* bin_out, unsigned* r_out) {
    __shared__ unsigned sums[256];
    __shared__ unsigned res[2];
    const int per = nbins / 256;
    const int t = threadIdx.x;
    unsigned local[16];
    unsigned s = 0;
    for (int j = 0; j < per; ++j) {
        local[j] = hist[nbins - 1 - (t * per + j)];
        s += local[j];
    }
    if (t == 0) { res[0] = 0u; res[1] = 1u; }
    sums[t] = s;
    __syncthreads();
    for (int off = 1; off < 256; off <<= 1) {
        unsigned v = (t >= off) ? sums[t - off] : 0u;
        __syncthreads();
        sums[t] += v;
        __syncthreads();
    }
    const unsigned incl = sums[t];
    const unsigned excl = incl - s;
    if (excl < R && incl >= R) {
        unsigned cum = excl;
        for (int j = 0; j < per; ++j) {
            if (cum + local[j] >= R) {
                res[0] = (unsigned)(nbins - 1 - (t * per + j));
                res[1] = R - cum;
                break;
            }
            cum += local[j];
        }
    }
    __syncthreads();
    *bin_out = res[0];
    *r_out = res[1];
    __syncthreads();
}

__device__ __forceinline__ bool hard_of(const Ctrl* c, unsigned Kneg) {
    return (c->cand_count < Kneg) || (c->maxkey >= FINE_LIMIT);
}

// ---------------- init: zero control region ----------------
__global__ void k_init(unsigned* ws) {
    const unsigned i = blockIdx.x * blockDim.x + threadIdx.x;
    const unsigned stride = gridDim.x * blockDim.x;
    for (unsigned j = i; j < CTRL_WORDS; j += stride) ws[j] = 0u;
}

// -------- main pass: pos_sum + ballot-aggregated compact (k >= K0) ---------
__global__ __launch_bounds__(256)
void k_main(const float* __restrict__ x, const float* __restrict__ y,
            Ctrl* __restrict__ ctrl, unsigned* __restrict__ cand,
            unsigned cap, int n) {
    __shared__ unsigned lbuf[LBUF_CAP];
    __shared__ unsigned s_u[3];          // lcount, gbase, kmax
    __shared__ float s_red;
    const int tid = threadIdx.x;
    const int lane = tid & 63;
    if (tid == 0) { s_u[0] = 0u; s_u[2] = 0u; s_red = 0.0f; }
    __syncthreads();
    float ps = 0.0f;
    unsigned kmax = 0u;
    const int n4 = n >> 2;
    const float4* x4 = (const float4*)x;
    const float4* y4 = (const float4*)y;
    const unsigned gtid = blockIdx.x * blockDim.x + tid;
    const unsigned gstride = gridDim.x * blockDim.x;
    for (unsigned i = gtid; i < (unsigned)n4; i += gstride) {
        float4 xv = x4[i];
        float4 yv = y4[i];
        float xs[4] = {xv.x, xv.y, xv.z, xv.w};
        float ys[4] = {yv.x, yv.y, yv.z, yv.w};
#pragma unroll
        for (int c = 0; c < 4; ++c) {
            bool pos = ys[c] > 0.0f;
            if (pos) ps += softplusf(-xs[c]);
            unsigned k = f2key(xs[c]);
            bool cnd = (!pos) && (k >= K0);
            if (cnd) kmax = max(kmax, k);
            unsigned long long mask = __ballot(cnd);
            if (mask) {
                unsigned pfx = __popcll(mask & ((1ull << lane) - 1ull));
                int leader = __ffsll((unsigned long long)mask) - 1;
                unsigned base = 0;
                if (lane == leader)
                    base = atomicAdd(&s_u[0], (unsigned)__popcll(mask));
                base = __shfl(base, leader);
                if (cnd) {
                    unsigned p = base + pfx;
                    if (p < LBUF_CAP) lbuf[p] = k;
                    else {   // overflow fallback (~640 cand/block expected)
                        unsigned gi = atomicAdd(&ctrl->cand_count, 1u);
                        if (gi < cap) cand[gi] = k;
                    }
                }
            }
        }
    }
    if (gtid == 0) {   // tail (n % 4)
        for (int i = (n >> 2) << 2; i < n; ++i) {
            float xs = x[i], ysv = y[i];
            if (ysv > 0.0f) ps += softplusf(-xs);
            else {
                unsigned k = f2key(xs);
                if (k >= K0) {
                    kmax = max(kmax, k);
                    unsigned p = atomicAdd(&s_u[0], 1u);
                    if (p < LBUF_CAP) lbuf[p] = k;
                    else {
                        unsigned gi = atomicAdd(&ctrl->cand_count, 1u);
                        if (gi < cap) cand[gi] = k;
                    }
                }
            }
        }
    }
    __syncthreads();
    ps = wred(ps);
    kmax = wredmax(kmax);
    if (lane == 0) { atomicAdd(&s_red, ps); atomicMax(&s_u[2], kmax); }
    __syncthreads();
    const unsigned m = s_u[0] < LBUF_CAP ? s_u[0] : LBUF_CAP;
    if (tid == 0) {
        s_u[1] = atomicAdd(&ctrl->cand_count, m);
        atomicAdd(&ctrl->pos_sum, s_red);
        if (s_u[2]) atomicMax(&ctrl->maxkey, s_u[2]);
    }
    __syncthreads();
    const unsigned gbase = s_u[1];
    for (unsigned i = tid; i < m; i += 256) {
        unsigned gi = gbase + i;
        if (gi < cap) cand[gi] = lbuf[i];
    }
}

// ---------------- stage 1: L1 histogram ----------------
__global__ __launch_bounds__(256)
void k_h1(const unsigned* __restrict__ cand, const float* __restrict__ x,
          const float* __restrict__ y, Ctrl* __restrict__ ctrl,
          const int* __restrict__ pos_num, unsigned cap, int n) {
    __shared__ unsigned h[NB1];
    for (int i = threadIdx.x; i < NB1; i += 256) h[i] = 0u;
    __syncthreads();
    const unsigned Kneg = (unsigned)(pos_num[0] * 3);
    const bool hard = hard_of(ctrl, Kneg);
    const unsigned mAll = ctrl->cand_count;
    const unsigned m = mAll < cap ? mAll : cap;
    const unsigned gtid = blockIdx.x * blockDim.x + threadIdx.x;
    const unsigned gstride = gridDim.x * blockDim.x;
    for (unsigned i = gtid; i < m; i += gstride)
        atomicAdd(&h[bin1_of(cand[i], hard)], 1u);
    if (hard) {
        for (unsigned i = gtid; i < (unsigned)n; i += gstride)
            if (y[i] == 0.0f) {
                unsigned k = f2key(x[i]);
                if (k < K0) atomicAdd(&h[k >> 20], 1u);
            }
    }
    __syncthreads();
    const unsigned rot = (blockIdx.x * 997u) & (NB1 - 1);
    for (int i = threadIdx.x; i < NB1; i += 256) {
        unsigned b = (i + rot) & (NB1 - 1);
        if (h[b]) atomicAdd(&ctrl->hist1[b], h[b]);
    }
}

// ---- stage 2: scan1 -> (b1,r1); sure-sum (bin1>b1); L2 hist (bin1==b1) ----
__global__ __launch_bounds__(256)
void k_h2(const unsigned* __restrict__ cand, const float* __restrict__ x,
          const float* __restrict__ y, Ctrl* __restrict__ ctrl,
          const int* __restrict__ pos_num, unsigned cap, int n) {
    __shared__ float s_red;
    const unsigned Kneg = (unsigned)(pos_num[0] * 3);
    const bool hard = hard_of(ctrl, Kneg);
    unsigned b1, r1;
    scan_desc(ctrl->hist1, NB1, Kneg, &b1, &r1);
    if (threadIdx.x == 0) s_red = 0.0f;
    __syncthreads();
    const unsigned mAll = ctrl->cand_count;
    const unsigned m = mAll < cap ? mAll : cap;
    const unsigned gtid = blockIdx.x * blockDim.x + threadIdx.x;
    const unsigned gstride = gridDim.x * blockDim.x;
    float ss = 0.0f;
    for (unsigned i = gtid; i < m; i += gstride) {
        unsigned k = cand[i];
        unsigned b = bin1_of(k, hard);
        if (b > b1) ss += softplusf(key2f(k));
        else if (b == b1) atomicAdd(&ctrl->hist2[bin2_of(k, hard)], 1u);
    }
    if (hard) {
        for (unsigned i = gtid; i < (unsigned)n; i += gstride)
            if (y[i] == 0.0f) {
                unsigned k = f2key(x[i]);
                if (k < K0) {
                    unsigned b = k >> 20;
                    if (b > b1) ss += softplusf(key2f(k));
                    else if (b == b1) atomicAdd(&ctrl->hist2[(k >> 10) & 1023u], 1u);
                }
            }
    }
    ss = wred(ss);
    if ((threadIdx.x & 63) == 0) atomicAdd(&s_red, ss);
    __syncthreads();
    if (threadIdx.x == 0) {
        atomicAdd(&ctrl->sum_sure, s_red);
        if (blockIdx.x == 0) { ctrl->b1 = b1; ctrl->r1 = r1; }
    }
}

// ---- stage 3: scan2 -> (b2,r2); l2-sure-sum; L3 hist (counts + f-sums) ----
__global__ __launch_bounds__(256)
void k_h3(const unsigned* __restrict__ cand, const float* __restrict__ x,
          const float* __restrict__ y, Ctrl* __restrict__ ctrl,
          const int* __restrict__ pos_num, unsigned cap, int n) {
    __shared__ float s_red;
    const unsigned Kneg = (unsigned)(pos_num[0] * 3);
    const bool hard = hard_of(ctrl, Kneg);
    const unsigned b1 = ctrl->b1;
    unsigned b2, r2;
    scan_desc(ctrl->hist2, NB2, ctrl->r1, &b2, &r2);
    if (threadIdx.x == 0) s_red = 0.0f;
    __syncthreads();
    const unsigned mAll = ctrl->cand_count;
    const unsigned m = mAll < cap ? mAll : cap;
    const unsigned gtid = blockIdx.x * blockDim.x + threadIdx.x;
    const unsigned gstride = gridDim.x * blockDim.x;
    float s2 = 0.0f;
    for (unsigned i = gtid; i < m; i += gstride) {
        unsigned k = cand[i];
        if (bin1_of(k, hard) == b1) {
            unsigned l2 = bin2_of(k, hard);
            if (l2 > b2) s2 += softplusf(key2f(k));
            else if (l2 == b2) {
                unsigned l3 = bin3_of(k, hard);
                atomicAdd(&ctrl->hist3[l3], 1u);
                atomicAdd(&ctrl->histF3[l3], softplusf(key2f(k)));
            }
        }
    }
    if (hard) {
        for (unsigned i = gtid; i < (unsigned)n; i += gstride)
            if (y[i] == 0.0f) {
                unsigned k = f2key(x[i]);
                if (k < K0 && (k >> 20) == b1) {
                    unsigned l2 = (k >> 10) & 1023u;
                    if (l2 > b2) s2 += softplusf(key2f(k));
                    else if (l2 == b2) {
                        atomicAdd(&ctrl->hist3[k & 1023u], 1u);
                        atomicAdd(&ctrl->histF3[k & 1023u], softplusf(key2f(k)));
                    }
                }
            }
    }
    s2 = wred(s2);
    if ((threadIdx.x & 63) == 0) atomicAdd(&s_red, s2);
    __syncthreads();
    if (threadIdx.x == 0) {
        atomicAdd(&ctrl->sum_l2, s_red);
        if (blockIdx.x == 0) { ctrl->b2 = b2; ctrl->r2 = r2; }
    }
}

// ---- final (1 block): scan3 -> exact H; combine all partial sums ----
__global__ __launch_bounds__(256)
void k_fin(Ctrl* __restrict__ ctrl, const int* __restrict__ pos_num,
           float* __restrict__ out) {
    __shared__ float s_red;
    const unsigned Kneg = (unsigned)(pos_num[0] * 3);
    const bool hard = hard_of(ctrl, Kneg);
    const unsigned b1 = ctrl->b1, b2 = ctrl->b2;
    unsigned c3, r3;
    scan_desc(ctrl->hist3, NB3, ctrl->r2, &c3, &r3);
    if (threadIdx.x == 0) s_red = 0.0f;
    __syncthreads();
    float s = 0.0f;
    for (unsigned j = c3 + 1 + threadIdx.x; j < NB3; j += 256)
        s += ctrl->histF3[j];
    s = wred(s);
    if ((threadIdx.x & 63) == 0) atomicAdd(&s_red, s);
    __syncthreads();
    if (threadIdx.x == 0) {
        unsigned H = hard ? ((b1 << 20) | (b2 << 10) | c3)
                          : (((C14 + b1) << 14) | (b2 << 4) | c3);
        float total = ctrl->pos_sum + ctrl->sum_sure + ctrl->sum_l2 +
                      s_red + (float)r3 * softplusf(key2f(H));
        int p = pos_num[0];
        out[0] = total / (float)(4 * p);
    }
}

extern "C" void kernel_launch(void* const* d_in, const int* in_sizes, int n_in,
                              void* d_out, int out_size, void* d_ws, size_t ws_size,
                              hipStream_t stream) {
    const float* x = (const float*)d_in[0];
    const float* y = (const float*)d_in[1];
    const int* pos_num = (const int*)d_in[2];
    float* out = (float*)d_out;
    const int n = in_sizes[0];

    unsigned* ws = (unsigned*)d_ws;
    Ctrl* ctrl = (Ctrl*)d_ws;
    unsigned* cand = ws + CTRL_WORDS;
    unsigned cap = (ws_size > (size_t)(CTRL_WORDS * 4))
                       ? (unsigned)((ws_size - CTRL_WORDS * 4) / 4)
                       : 0u;

    k_init<<<32, 256, 0, stream>>>(ws);
    k_main<<<2048, 256, 0, stream>>>(x, y, ctrl, cand, cap, n);
    k_h1<<<128, 256, 0, stream>>>(cand, x, y, ctrl, pos_num, cap, n);
    k_h2<<<256, 256, 0, stream>>>(cand, x, y, ctrl, pos_num, cap, n);
    k_h3<<<256, 256, 0, stream>>>(cand, x, y, ctrl, pos_num, cap, n);
    k_fin<<<1, 256, 0, stream>>>(ctrl, pos_num, out);
}

// Round 7
// 146.377 us; speedup vs baseline: 6.4584x; 1.3882x over previous
//
#include <hip/hip_runtime.h>
#include <math.h>

// OHNM loss: pos BCE sum + top-k(600000) negative softplus sum, mean over 800000.
//
// R7: ZERO contended RMWs. Model from R1/R4/R5/R6: device atomics to one
// contended line cost ~7ns each (XCD ping-pong); R4/R6 k_main epilogues spent
// 30-45us on cand_count/pos_sum/maxkey RMWs sharing one Ctrl line.
// Design: per-WAVE private cand regions (cursor = uniform register via
// ballot+popc, plain stores only); per-wave counts/posp/maxk slots (stores);
// k_red1 reduces them; k_h1 writes 64 PRIVATE partial histograms (no merge
// atomics) summed inside k_h2's scan. Only ~9K scattered atomics remain
// (boundary-bin keys -> hist2; ~dozens -> hist3).
// Radix (fine): kp=k-K0; L1=kp>>16 (1024 bins over x in [1,256)),
// L2=bits15:4 (4096), L3=bits3:0 -> ties-bin keys fully determined.
// hard mode (count shortfall / region overflow / x>=256): coarse
// L1=k>>22, L2=bits21:10, L3=bits9:0 re-streamed from x,y. Never taken here.

#define K0 0xBF800000u             // f2key(1.0f)
#define FINE_LIMIT 0xC3800000u     // f2key(256.0f)
#define NWAVES 8192                // k_main: 2048 blocks x 4 waves
#define REG 256                    // cand words per wave (lambda=159, +7.9 sigma)
#define NH1 64                     // partial histograms (k_h1 blocks)

// ---- ws layout (word offsets) ----
#define CTRL_W   8192              // Ctrl struct area (32 KB)
#define OFF_H1P  (CTRL_W)                     // 64 x 1024
#define OFF_CNT  (OFF_H1P + NH1 * 1024)      // 8192
#define OFF_POSP (OFF_CNT + NWAVES)          // 8192 (float)
#define OFF_MAXK (OFF_POSP + NWAVES)         // 8192
#define OFF_SURE (OFF_MAXK + NWAVES)         // 64 (float)
#define OFF_L2P  (OFF_SURE + 64)             // 64 (float)
#define OFF_CAND (OFF_L2P + 64)
#define CANDW    (NWAVES * REG)              // 2,097,152 words (8 MB)

struct Ctrl {
    unsigned hist2[4096];
    unsigned hist3[1024];
    float    histF3[1024];
    float    pos_sum;
    unsigned cand_count;
    unsigned maxkey;
    unsigned hard;
    unsigned b1, r1, b2, r2;
};

__device__ __forceinline__ unsigned f2key(float x) {
    unsigned u = __float_as_uint(x);
    return (u & 0x80000000u) ? ~u : (u | 0x80000000u);
}
__device__ __forceinline__ float key2f(unsigned k) {
    unsigned u = (k & 0x80000000u) ? (k & 0x7FFFFFFFu) : ~k;
    return __uint_as_float(u);
}
__device__ __forceinline__ float softplusf(float x) {
    return fmaxf(x, 0.0f) + __logf(1.0f + __expf(-fabsf(x)));
}
__device__ __forceinline__ float wred(float v) {
    v += __shfl_down(v, 32); v += __shfl_down(v, 16); v += __shfl_down(v, 8);
    v += __shfl_down(v, 4);  v += __shfl_down(v, 2);  v += __shfl_down(v, 1);
    return v;
}
__device__ __forceinline__ unsigned wredmax(unsigned v) {
    v = max(v, (unsigned)__shfl_down((int)v, 32));
    v = max(v, (unsigned)__shfl_down((int)v, 16));
    v = max(v, (unsigned)__shfl_down((int)v, 8));
    v = max(v, (unsigned)__shfl_down((int)v, 4));
    v = max(v, (unsigned)__shfl_down((int)v, 2));
    v = max(v, (unsigned)__shfl_down((int)v, 1));
    return v;
}
// block float-sum; result valid on thread 0
__device__ float bred(float v) {
    __shared__ float sb[16];
    const int lane = threadIdx.x & 63, w = threadIdx.x >> 6;
    const int nw = blockDim.x >> 6;
    v = wred(v);
    if (lane == 0) sb[w] = v;
    __syncthreads();
    float r = 0.0f;
    if (threadIdx.x == 0) for (int i = 0; i < nw; ++i) r += sb[i];
    __syncthreads();
    return r;
}

// descending rank-select, summing nparts partial hists; redundant per block.
// All NT threads call. First bin (from top) with cum >= R; r = R - above (>=1).
template<int NT>
__device__ void scan_desc(const unsigned* __restrict__ hist, int nparts,
                          int pstride, int nbins, unsigned R,
                          unsigned* bin_out, unsigned* r_out) {
    __shared__ unsigned sums[NT];
    __shared__ unsigned res[2];
    const int per = nbins / NT;
    const int t = threadIdx.x;
    unsigned local[8];
    unsigned s = 0;
    for (int j = 0; j < per; ++j) {
        const int bin = nbins - 1 - (t * per + j);
        unsigned v = 0;
        for (int p = 0; p < nparts; ++p) v += hist[p * pstride + bin];
        local[j] = v;
        s += v;
    }
    if (t == 0) { res[0] = 0u; res[1] = 1u; }
    sums[t] = s;
    __syncthreads();
    for (int off = 1; off < NT; off <<= 1) {
        unsigned v = (t >= off) ? sums[t - off] : 0u;
        __syncthreads();
        sums[t] += v;
        __syncthreads();
    }
    const unsigned incl = sums[t], excl = incl - s;
    if (excl < R && incl >= R) {
        unsigned cum = excl;
        for (int j = 0; j < per; ++j) {
            if (cum + local[j] >= R) {
                res[0] = (unsigned)(nbins - 1 - (t * per + j));
                res[1] = R - cum;
                break;
            }
            cum += local[j];
        }
    }
    __syncthreads();
    *bin_out = res[0];
    *r_out = res[1];
    __syncthreads();
}

// fine bins: kp = k - K0 (only for k in [K0, FINE_LIMIT))
__device__ __forceinline__ unsigned fl1(unsigned kp) { return kp >> 16; }
__device__ __forceinline__ unsigned fl2(unsigned kp) { return (kp >> 4) & 0xFFFu; }
__device__ __forceinline__ unsigned fl3(unsigned kp) { return kp & 0xFu; }
// hard bins: full key range
__device__ __forceinline__ unsigned hl1(unsigned k) { return k >> 22; }
__device__ __forceinline__ unsigned hl2(unsigned k) { return (k >> 10) & 0xFFFu; }
__device__ __forceinline__ unsigned hl3(unsigned k) { return k & 0x3FFu; }

// ---- k_main: pos_sum + per-wave-region compact. ZERO atomics. ----
__global__ __launch_bounds__(256)
void k_main(const float* __restrict__ x, const float* __restrict__ y,
            unsigned* __restrict__ ws, unsigned cap_words, int n) {
    const int tid = threadIdx.x;
    const int lane = tid & 63;
    const unsigned waveid = blockIdx.x * 4 + (tid >> 6);
    unsigned* cand = ws + OFF_CAND;
    const unsigned base = waveid * REG;

    float ps = 0.0f;
    unsigned kmax = 0u, cur = 0u, ovf = 0u;
    const int n4 = n >> 2;
    const float4* x4 = (const float4*)x;
    const float4* y4 = (const float4*)y;
    const unsigned gtid = blockIdx.x * blockDim.x + tid;
    const unsigned gstride = gridDim.x * blockDim.x;
    for (unsigned i = gtid; i < (unsigned)n4; i += gstride) {
        float4 xv = x4[i];
        float4 yv = y4[i];
        float xs[4] = {xv.x, xv.y, xv.z, xv.w};
        float ys[4] = {yv.x, yv.y, yv.z, yv.w};
#pragma unroll
        for (int c = 0; c < 4; ++c) {
            bool pos = ys[c] > 0.0f;
            if (pos) ps += softplusf(-xs[c]);
            unsigned k = f2key(xs[c]);
            bool cnd = (!pos) && (k >= K0);
            unsigned long long mask = __ballot(cnd);
            if (mask) {
                if (cnd) {
                    kmax = max(kmax, k);
                    unsigned slot = cur + (unsigned)__popcll(mask & ((1ull << lane) - 1ull));
                    unsigned gi = base + slot;
                    if (slot < REG && gi < cap_words) cand[gi] = k;
                    else ovf = 1u;
                }
                cur += (unsigned)__popcll(mask);
            }
        }
    }
    // tail (n % 4): wave 0, all lanes (keeps cur uniform)
    if (waveid == 0) {
        for (int i = (n & ~3) + lane; i < n; i += 64) {
            float xs = x[i];
            bool pos = y[i] > 0.0f;
            if (pos) ps += softplusf(-xs);
            unsigned k = f2key(xs);
            bool cnd = (!pos) && (k >= K0);
            unsigned long long mask = __ballot(cnd);
            if (mask) {
                if (cnd) {
                    kmax = max(kmax, k);
                    unsigned slot = cur + (unsigned)__popcll(mask & ((1ull << lane) - 1ull));
                    unsigned gi = base + slot;
                    if (slot < REG && gi < cap_words) cand[gi] = k;
                    else ovf = 1u;
                }
                cur += (unsigned)__popcll(mask);
            }
        }
    }
    // zero-fill padding (stage kernels skip k < K0; 0 < K0)
    for (unsigned j = cur + lane; j < REG; j += 64) {
        unsigned gi = base + j;
        if (gi < cap_words) cand[gi] = 0u;
    }
    if (base + REG > cap_words) ovf = 1u;     // region didn't fit
    // per-wave result slots: plain stores, zero contention
    ps = wred(ps);
    kmax = wredmax(kmax);
    unsigned anyovf = (__ballot(ovf != 0u) != 0ull) ? 0x80000000u : 0u;
    if (lane == 0) {
        ws[OFF_CNT + waveid] = (cur & 0x7FFFFFFFu) | anyovf;
        ((float*)ws)[OFF_POSP + waveid] = ps;
        ws[OFF_MAXK + waveid] = kmax;
    }
}

// ---- k_red1 (1 block): reduce per-wave slots; set mode; zero hist2/3 ----
__global__ __launch_bounds__(1024)
void k_red1(unsigned* __restrict__ ws, const int* __restrict__ pos_num) {
    __shared__ float sf[16];
    __shared__ unsigned st[16], sm[16], so[16];
    Ctrl* c = (Ctrl*)ws;
    const int t = threadIdx.x, lane = t & 63, w = t >> 6;
    unsigned tot = 0u, mk = 0u, ov = 0u;
    float ps = 0.0f;
    for (unsigned i = t; i < NWAVES; i += 1024) {
        unsigned cc = ws[OFF_CNT + i];
        tot += cc & 0x7FFFFFFFu;
        ov |= cc >> 31;
        mk = max(mk, ws[OFF_MAXK + i]);
        ps += ((float*)ws)[OFF_POSP + i];
    }
    ps = wred(ps);
    tot += __shfl_down(tot, 32); tot += __shfl_down(tot, 16);
    tot += __shfl_down(tot, 8);  tot += __shfl_down(tot, 4);
    tot += __shfl_down(tot, 2);  tot += __shfl_down(tot, 1);
    mk = wredmax(mk);
    ov |= (unsigned)__shfl_down((int)ov, 32); ov |= (unsigned)__shfl_down((int)ov, 16);
    ov |= (unsigned)__shfl_down((int)ov, 8);  ov |= (unsigned)__shfl_down((int)ov, 4);
    ov |= (unsigned)__shfl_down((int)ov, 2);  ov |= (unsigned)__shfl_down((int)ov, 1);
    if (lane == 0) { sf[w] = ps; st[w] = tot; sm[w] = mk; so[w] = ov; }
    __syncthreads();
    if (t == 0) {
        float P = 0; unsigned T = 0, M = 0, O = 0;
        for (int i = 0; i < 16; ++i) { P += sf[i]; T += st[i]; M = max(M, sm[i]); O |= so[i]; }
        const unsigned Kneg = (unsigned)(pos_num[0] * 3);
        c->pos_sum = P;
        c->cand_count = T;
        c->maxkey = M;
        c->hard = (T < Kneg) || (M >= FINE_LIMIT) || O;
    }
    // zero hist2 + hist3 + histF3 (6144 words)
    for (int i = t; i < 4096; i += 1024) c->hist2[i] = 0u;
    for (int i = t; i < 1024; i += 1024) { c->hist3[i] = 0u; c->histF3[i] = 0.0f; }
}

// ---- k_h1 (64 x 1024): private partial L1 histograms, pure stores ----
__global__ __launch_bounds__(1024)
void k_h1(const float* __restrict__ x, const float* __restrict__ y,
          unsigned* __restrict__ ws, unsigned cap_words, int n) {
    __shared__ unsigned h[1024];
    Ctrl* c = (Ctrl*)ws;
    const unsigned* cand = ws + OFF_CAND;
    const int t = threadIdx.x;
    h[t] = 0u;
    __syncthreads();
    const bool hard = c->hard != 0u;
    const unsigned gtid = blockIdx.x * blockDim.x + t;
    const unsigned gstride = gridDim.x * blockDim.x;
    if (!hard) {
        const unsigned lim = CANDW < cap_words ? (unsigned)CANDW : cap_words;
        for (unsigned i = gtid; i < lim; i += gstride) {
            unsigned k = cand[i];
            if (k >= K0) atomicAdd(&h[fl1(k - K0)], 1u);
        }
    } else {
        for (unsigned i = gtid; i < (unsigned)n; i += gstride)
            if (y[i] == 0.0f) atomicAdd(&h[hl1(f2key(x[i]))], 1u);
    }
    __syncthreads();
    ws[OFF_H1P + blockIdx.x * 1024 + t] = h[t];   // pure store
}

// ---- k_h2 (64 x 1024): scan1 from partials; sure-sum; hist2 (scattered) ----
__global__ __launch_bounds__(1024)
void k_h2(const float* __restrict__ x, const float* __restrict__ y,
          unsigned* __restrict__ ws, const int* __restrict__ pos_num,
          unsigned cap_words, int n) {
    Ctrl* c = (Ctrl*)ws;
    const unsigned* cand = ws + OFF_CAND;
    const bool hard = c->hard != 0u;
    const unsigned Kneg = (unsigned)(pos_num[0] * 3);
    unsigned b1, r1;
    scan_desc<1024>(ws + OFF_H1P, NH1, 1024, 1024, Kneg, &b1, &r1);
    const unsigned gtid = blockIdx.x * blockDim.x + threadIdx.x;
    const unsigned gstride = gridDim.x * blockDim.x;
    float ss = 0.0f;
    if (!hard) {
        const unsigned lim = CANDW < cap_words ? (unsigned)CANDW : cap_words;
        for (unsigned i = gtid; i < lim; i += gstride) {
            unsigned k = cand[i];
            if (k >= K0) {
                unsigned kp = k - K0;
                unsigned b = fl1(kp);
                if (b > b1) ss += softplusf(key2f(k));
                else if (b == b1) atomicAdd(&c->hist2[fl2(kp)], 1u);
            }
        }
    } else {
        for (unsigned i = gtid; i < (unsigned)n; i += gstride)
            if (y[i] == 0.0f) {
                unsigned k = f2key(x[i]);
                unsigned b = hl1(k);
                if (b > b1) ss += softplusf(key2f(k));
                else if (b == b1) atomicAdd(&c->hist2[hl2(k)], 1u);
            }
    }
    ss = bred(ss);
    if (threadIdx.x == 0) {
        ((float*)ws)[OFF_SURE + blockIdx.x] = ss;   // private slot
        if (blockIdx.x == 0) { c->b1 = b1; c->r1 = r1; }
    }
}

// ---- k_h3 (64 x 1024): scan2; l2-sure-sum; hist3/histF3 (tiny) ----
__global__ __launch_bounds__(1024)
void k_h3(const float* __restrict__ x, const float* __restrict__ y,
          unsigned* __restrict__ ws, unsigned cap_words, int n) {
    Ctrl* c = (Ctrl*)ws;
    const unsigned* cand = ws + OFF_CAND;
    const bool hard = c->hard != 0u;
    const unsigned b1 = c->b1, r1 = c->r1;
    unsigned b2, r2;
    scan_desc<1024>(c->hist2, 1, 0, 4096, r1, &b2, &r2);
    const unsigned gtid = blockIdx.x * blockDim.x + threadIdx.x;
    const unsigned gstride = gridDim.x * blockDim.x;
    float s2 = 0.0f;
    if (!hard) {
        const unsigned lim = CANDW < cap_words ? (unsigned)CANDW : cap_words;
        for (unsigned i = gtid; i < lim; i += gstride) {
            unsigned k = cand[i];
            if (k >= K0) {
                unsigned kp = k - K0;
                if (fl1(kp) == b1) {
                    unsigned l2 = fl2(kp);
                    if (l2 > b2) s2 += softplusf(key2f(k));
                    else if (l2 == b2) {
                        atomicAdd(&c->hist3[fl3(kp)], 1u);
                        atomicAdd(&c->histF3[fl3(kp)], softplusf(key2f(k)));
                    }
                }
            }
        }
    } else {
        for (unsigned i = gtid; i < (unsigned)n; i += gstride)
            if (y[i] == 0.0f) {
                unsigned k = f2key(x[i]);
                if (hl1(k) == b1) {
                    unsigned l2 = hl2(k);
                    if (l2 > b2) s2 += softplusf(key2f(k));
                    else if (l2 == b2) {
                        atomicAdd(&c->hist3[hl3(k)], 1u);
                        atomicAdd(&c->histF3[hl3(k)], softplusf(key2f(k)));
                    }
                }
            }
    }
    s2 = bred(s2);
    if (threadIdx.x == 0) {
        ((float*)ws)[OFF_L2P + blockIdx.x] = s2;    // private slot
        if (blockIdx.x == 0) { c->b2 = b2; c->r2 = r2; }
    }
}

// ---- k_fin (1 x 256): scan3; combine everything ----
__global__ __launch_bounds__(256)
void k_fin(unsigned* __restrict__ ws, const int* __restrict__ pos_num,
           float* __restrict__ out) {
    Ctrl* c = (Ctrl*)ws;
    const bool hard = c->hard != 0u;
    const unsigned b1 = c->b1, b2 = c->b2, r2 = c->r2;
    unsigned c3, r3;
    scan_desc<256>(c->hist3, 1, 0, 1024, r2, &c3, &r3);
    const int t = threadIdx.x;
    float s = 0.0f;
    for (int i = t; i < 64; i += 256)
        s += ((float*)ws)[OFF_SURE + i] + ((float*)ws)[OFF_L2P + i];
    for (unsigned j = c3 + 1 + t; j < 1024; j += 256)
        s += c->histF3[j];
    s = bred(s);
    if (t == 0) {
        unsigned H = hard ? ((b1 << 22) | (b2 << 10) | c3)
                          : (K0 + ((b1 << 16) | (b2 << 4) | c3));
        float total = c->pos_sum + s + (float)r3 * softplusf(key2f(H));
        int p = pos_num[0];
        out[0] = total / (float)(4 * p);
    }
}

extern "C" void kernel_launch(void* const* d_in, const int* in_sizes, int n_in,
                              void* d_out, int out_size, void* d_ws, size_t ws_size,
                              hipStream_t stream) {
    const float* x = (const float*)d_in[0];
    const float* y = (const float*)d_in[1];
    const int* pos_num = (const int*)d_in[2];
    float* out = (float*)d_out;
    const int n = in_sizes[0];

    unsigned* ws = (unsigned*)d_ws;
    // cand capacity in words, relative to ws start (cand lives at OFF_CAND)
    unsigned cap_words = 0u;
    if (ws_size / 4 > (size_t)OFF_CAND)
        cap_words = (unsigned)(ws_size / 4 - OFF_CAND);
    if (cap_words > (unsigned)CANDW) cap_words = (unsigned)CANDW;

    k_main<<<2048, 256, 0, stream>>>(x, y, ws, cap_words, n);
    k_red1<<<1, 1024, 0, stream>>>(ws, pos_num);
    k_h1<<<NH1, 1024, 0, stream>>>(x, y, ws, cap_words, n);
    k_h2<<<NH1, 1024, 0, stream>>>(x, y, ws, pos_num, cap_words, n);
    k_h3<<<NH1, 1024, 0, stream>>>(x, y, ws, cap_words, n);
    k_fin<<<1, 256, 0, stream>>>(ws, pos_num, out);
}